// Round 8
// baseline (142.683 us; speedup 1.0000x reference)
//
#include <hip/hip_runtime.h>
#include <hip/hip_bf16.h>
#include <math.h>

// Problem constants (fixed by setup_inputs)
#define M_TOT 2
#define N_TOT 4096
#define DZ    64
#define G_TOT 16384

// Tiling: 256-thread blocks (4 waves), each wave owns 32 g-rows (2 A-frag groups).
// Grid = 128 g-blocks x 2 m x 4 n-splits = 1024 blocks -> 16 waves/CU (4/SIMD).
// Session evidence: 16 waves/CU (R4, 58us) beats all 8-waves/CU variants (R5/R7,
// 74-76us) regardless of per-wave efficiency — residency is the dominant lever.
// NSPLIT=4: fp32 atomic split-K cheap at 4-way (32 MB writes), superlinear at 8.
#define BG      128
#define BN      64
#define THREADS 256
#define NSPLIT  4
#define NCHUNK  (N_TOT / NSPLIT)   // 1024
#define ITERS   (NCHUNK / BN)      // 16
// zT: bf16 [dz=64][n=64], row = 128 B. XOR swizzle of the 16B block:
// phys = logical ^ swz(row), swz(r) = ((r>>1)&7) ^ (r>>4).
// Floor-optimal for b64 staging writes (4 dw/bank) and b128 B-frag reads
// (8 dw/bank) — R6/R7 measured 524K conflicts. k-order in 16B blocks preserved.
// k-data (x coords) is NOT staged: quad-uniform global loads (L1-resident 32 KB)
// + packed VALU recompute. LDS reads = 8 b128/wave-iter (vs R4's 20).
#define ZROW_B  128
#define BUF_B   (DZ * ZROW_B)      // 8192 bytes per pipeline buffer (zT only)

typedef __attribute__((ext_vector_type(8))) short  short8;  // 8 bf16 MFMA A/B frag
typedef __attribute__((ext_vector_type(4))) float  f32x4;   // MFMA C/D frag
typedef __attribute__((ext_vector_type(2))) float  f32x2;   // packed fp32 (v_pk_*_f32)
typedef __attribute__((ext_vector_type(4))) int    int4v;

#if __has_builtin(__builtin_amdgcn_cvt_pk_bf16_f32)
__device__ __forceinline__ unsigned int pack_bf16_pair(float lo, float hi) {
    return __builtin_bit_cast(unsigned int, __builtin_amdgcn_cvt_pk_bf16_f32(lo, hi));
}
#else
__device__ __forceinline__ unsigned int pack_bf16_pair(float lo, float hi) {
    const unsigned int a = __float_as_uint(lo) + 0x8000u;  // round-half-up to bf16
    const unsigned int b = __float_as_uint(hi) + 0x8000u;
    return __builtin_amdgcn_perm(b, a, 0x07060302u);       // [lo[31:16], hi[31:16]]
}
#endif

__global__ __launch_bounds__(THREADS, 4)
void setconv_kernel(const float* __restrict__ x,       // [2][4096][2]
                    const float* __restrict__ z,       // [2][4096][64]
                    const float* __restrict__ x_grid,  // [2][16384][2]
                    const float* __restrict__ z_grid,  // [2][16384][64]
                    const float* __restrict__ lsp,     // [2]
                    float* __restrict__ out)           // [2][16384][64], memset to 0
{
    __shared__ __align__(16) unsigned char lds[2 * BUF_B];

    const int tid  = threadIdx.x;
    const int wave = tid >> 6;
    const int lane = tid & 63;
    const int quad = lane >> 4;
    const int l16  = lane & 15;

    const int mb    = blockIdx.y;
    const int gbase = blockIdx.x * BG;
    const int nbase = blockIdx.z * NCHUNK;

    const float LOG2E = 1.44269504088896340736f;
    const float inv0 = 1.0f / (1e-5f + log1pf(__expf(lsp[0])));
    const float inv1 = 1.0f / (1e-5f + log1pf(__expf(lsp[1])));
    const f32x2 inv02 = (f32x2){inv0, inv0};
    const f32x2 inv12 = (f32x2){inv1, inv1};
    const f32x2 nh2   = (f32x2){-0.5f * LOG2E, -0.5f * LOG2E};

    // 2 row-groups per wave: rows wave*32 + g*16 + l16 (splat to f32x2 for pk math).
    f32x2 qx2[2], qy2[2], hq2[2];
#pragma unroll
    for (int g = 0; g < 2; g++) {
        const int grow = gbase + wave * 32 + g * 16 + l16;
        const float2 qraw = *(const float2*)&x_grid[(size_t)(mb * G_TOT + grow) * 2];
        const float qx = qraw.x * inv0, qy = qraw.y * inv1;
        const float qxL = LOG2E * qx, qyL = LOG2E * qy;
        const float hq  = -0.5f * LOG2E * (qx * qx + qy * qy);
        qx2[g] = (f32x2){qxL, qxL};
        qy2[g] = (f32x2){qyL, qyL};
        hq2[g] = (f32x2){hq, hq};
    }

    // z staging: sdzg = dz-group of 4 (consecutive lanes -> consecutive dz ->
    // 256B-coalesced float4 global loads), snq = n-quad (n = snq*4 + j).
    const int sdzg = tid & 15;
    const int snq  = tid >> 4;     // 0..15
    const float* zb = z + (size_t)mb * N_TOT * DZ + sdzg * 4;
    // Write offsets: row d = sdzg*4+i, logical block = snq>>1, sub = (snq&1)*8,
    // phys = (snq>>1) ^ ((2*(sdzg&3) + (i>>1)) & 7) ^ (sdzg>>2).
    unsigned wr_off[4];
#pragma unroll
    for (int i = 0; i < 4; i++) {
        const unsigned swz  = ((2u * (sdzg & 3) + (i >> 1)) & 7u) ^ (unsigned)(sdzg >> 2);
        const unsigned phys = ((unsigned)(snq >> 1)) ^ swz;
        wr_off[i] = (unsigned)(sdzg * 4 + i) * ZROW_B + phys * 16 + (unsigned)(snq & 1) * 8;
    }

    // B-frag read bases: row r = nt*16 + l16 -> swz = ((l16>>1)&7) ^ nt;
    // block = quad ^ (kc<<2). addr = l16*128 + nt*2048 + ((quad^(kc<<2)^swz^nt)*16).
    const unsigned swz_l = (unsigned)((l16 >> 1) & 7);
    const unsigned rbA   = (unsigned)l16 * ZROW_B + ((unsigned)quad ^ swz_l) * 16;  // kc=0, nt=0
    const unsigned rbB   = rbA ^ (4u * 16u);                                        // kc=1, nt=0

    f32x4 acc[2][4];
#pragma unroll
    for (int g = 0; g < 2; g++)
#pragma unroll
        for (int i = 0; i < 4; i++) acc[g][i] = (f32x4){0.f, 0.f, 0.f, 0.f};

    // k-coordinate loads: quad-uniform addresses -> L1-broadcast (x is 32 KB/m,
    // L1/L2-resident). Issued at iteration top; latency hides under ds_reads.
    const float* xk = x + (size_t)mb * N_TOT * 2;

    auto loadz = [&](int n0, float4* zf) {
        const float* zp = zb + (size_t)(n0 + snq * 4) * DZ;
#pragma unroll
        for (int j = 0; j < 4; j++) zf[j] = *(const float4*)(zp + j * DZ);
    };
    auto stagez = [&](unsigned dst, const float4* zf) {
#pragma unroll
        for (int i = 0; i < 4; i++) {
            uint2 w;
            w.x = pack_bf16_pair(zf[0][i], zf[1][i]);
            w.y = pack_bf16_pair(zf[2][i], zf[3][i]);
            *(uint2*)(lds + dst + wr_off[i]) = w;
        }
    };

    // ---- prologue: fetch + stage tile 0 ----
    float4 zf[4];
    loadz(nbase, zf);
    stagez(0u, zf);
    __syncthreads();

    for (int t = 0; t < ITERS; t++) {
        const unsigned bo = (unsigned)((t & 1) ? BUF_B : 0);
        const unsigned bn = bo ^ (unsigned)BUF_B;
        const int n0 = nbase + t * BN;

        // ---- issue next z-tile's global loads (latency hidden under compute) ----
        float4 zfn[4];
        if (t + 1 < ITERS) loadz(n0 + BN, zfn);

        // ---- k coords for this tile (quad-uniform, L1-hit) ----
        float4 kf[8];
#pragma unroll
        for (int kc = 0; kc < 2; kc++)
#pragma unroll
            for (int j = 0; j < 4; j++)   // float4 = coords of n-pair (2j, 2j+1)
                kf[kc * 4 + j] =
                    *(const float4*)(xk + (size_t)(n0 + kc * 32 + quad * 8 + j * 2) * 2);

        // ---- compute tile t ----
#pragma unroll
        for (int kc = 0; kc < 2; kc++) {
            // B-frags once per kc, reused by both row-groups.
            short8 bf[4];
            const unsigned rb = bo + ((kc == 0) ? rbA : rbB);
#pragma unroll
            for (int nt = 0; nt < 4; nt++)
                bf[nt] = *(const short8*)(lds + (rb ^ (unsigned)(nt * 16)) + nt * (16 * ZROW_B));

            // k-prep in registers (packed): u=kx/ls0, v=ky/ls1, hb=-0.5L(u^2+v^2).
            f32x2 u2[4], v2[4], hb2[4];
#pragma unroll
            for (int j = 0; j < 4; j++) {
                const float4 f = kf[kc * 4 + j];   // (kx0,ky0,kx1,ky1)
                u2[j] = (f32x2){f.x, f.z} * inv02;
                v2[j] = (f32x2){f.y, f.w} * inv12;
                f32x2 tt = u2[j] * u2[j];
                tt = __builtin_elementwise_fma(v2[j], v2[j], tt);
                hb2[j] = tt * nh2;
            }

            // Scores (v_pk_fma_f32) -> exp2 -> bf16 A-frags -> 8 MFMA.
#pragma unroll
            for (int g = 0; g < 2; g++) {
                unsigned aw[4];
#pragma unroll
                for (int j = 0; j < 4; j++) {
                    f32x2 s = hq2[g] + hb2[j];
                    s = __builtin_elementwise_fma(qy2[g], v2[j], s);
                    s = __builtin_elementwise_fma(qx2[g], u2[j], s);
                    aw[j] = pack_bf16_pair(__builtin_amdgcn_exp2f(s.x),
                                           __builtin_amdgcn_exp2f(s.y));
                }
                const int4v  av = {(int)aw[0], (int)aw[1], (int)aw[2], (int)aw[3]};
                const short8 af = __builtin_bit_cast(short8, av);
#pragma unroll
                for (int nt = 0; nt < 4; nt++)
                    acc[g][nt] = __builtin_amdgcn_mfma_f32_16x16x32_bf16(af, bf[nt], acc[g][nt], 0, 0, 0);
            }
        }

        // ---- stage next tile into buffer bn; single barrier per iteration ----
        if (t + 1 < ITERS) {
            stagez(bn, zfn);
            __syncthreads();
        }
    }

    // ---- epilogue: C/D layout col = lane&15 (dz), row = quad*4 + reg (g-row) ----
    // out was memset to 0; 4 n-splits combine via atomics. Split 0 folds z_grid in.
    const bool add_zg = (blockIdx.z == 0);
#pragma unroll
    for (int g = 0; g < 2; g++) {
        const int gout = gbase + wave * 32 + g * 16 + quad * 4;
#pragma unroll
        for (int nt = 0; nt < 4; nt++) {
#pragma unroll
            for (int r = 0; r < 4; r++) {
                const size_t idx = (size_t)(mb * G_TOT + gout + r) * DZ + nt * 16 + l16;
                const float v = add_zg ? (acc[g][nt][r] + z_grid[idx]) : acc[g][nt][r];
                atomicAdd(&out[idx], v);
            }
        }
    }
}

extern "C" void kernel_launch(void* const* d_in, const int* in_sizes, int n_in,
                              void* d_out, int out_size, void* d_ws, size_t ws_size,
                              hipStream_t stream) {
    const float* x   = (const float*)d_in[0];
    const float* z   = (const float*)d_in[1];
    const float* xg  = (const float*)d_in[2];
    const float* zgr = (const float*)d_in[3];
    const float* lsp = (const float*)d_in[4];
    float* out = (float*)d_out;

    // out = 0 (write-only memset node; z_grid folded in by split 0's atomics)
    hipMemsetAsync(out, 0, sizeof(float) * (size_t)M_TOT * G_TOT * DZ, stream);

    dim3 grid(G_TOT / BG, M_TOT, NSPLIT);
    setconv_kernel<<<grid, THREADS, 0, stream>>>(x, z, xg, zgr, lsp, out);
}

// Round 9
// 132.900 us; speedup vs baseline: 1.0736x; 1.0736x over previous
//
#include <hip/hip_runtime.h>
#include <hip/hip_bf16.h>
#include <math.h>

// Problem constants (fixed by setup_inputs)
#define M_TOT 2
#define N_TOT 4096
#define DZ    64
#define G_TOT 16384

// Tiling: 256-thread blocks (4 waves), each wave owns 32 g-rows (2 A-frag groups).
// Grid = 128 g-blocks x 2 m x 4 n-splits = 1024 blocks -> 16 waves/CU (4/SIMD).
// Session evidence: 16 waves/CU is mandatory (R4 58us vs R5/R7 74-76us at 8 w/CU);
// k-data must be REGISTER-PREFETCHED one iteration ahead (R8's in-loop k-loads
// forced vmcnt(0) each iter, draining the z-prefetch -> 82us + 7MB extra FETCH).
// NSPLIT=4: fp32 atomic split-K cheap at 4-way (32 MB writes), superlinear at 8 (R6).
#define BG      128
#define BN      64
#define THREADS 256
#define NSPLIT  4
#define NCHUNK  (N_TOT / NSPLIT)   // 1024
#define ITERS   (NCHUNK / BN)      // 16
// zT: bf16 [dz=64][n=64], row = 128 B. XOR swizzle of the 16B block:
// phys = logical ^ swz(row), swz(r) = ((r>>1)&7) ^ (r>>4).
// Floor-optimal for b64 staging writes (4 dw/bank) and b128 B-frag reads
// (8 dw/bank). k-order in 16B blocks preserved.
#define ZROW_B  128
#define BUF_B   (DZ * ZROW_B)      // 8192 bytes per pipeline buffer (zT only)

typedef __attribute__((ext_vector_type(8))) short  short8;  // 8 bf16 MFMA A/B frag
typedef __attribute__((ext_vector_type(4))) float  f32x4;   // MFMA C/D frag
typedef __attribute__((ext_vector_type(2))) float  f32x2;   // packed fp32 (v_pk_*_f32)
typedef __attribute__((ext_vector_type(4))) int    int4v;

#if __has_builtin(__builtin_amdgcn_cvt_pk_bf16_f32)
__device__ __forceinline__ unsigned int pack_bf16_pair(float lo, float hi) {
    return __builtin_bit_cast(unsigned int, __builtin_amdgcn_cvt_pk_bf16_f32(lo, hi));
}
#else
__device__ __forceinline__ unsigned int pack_bf16_pair(float lo, float hi) {
    const unsigned int a = __float_as_uint(lo) + 0x8000u;  // round-half-up to bf16
    const unsigned int b = __float_as_uint(hi) + 0x8000u;
    return __builtin_amdgcn_perm(b, a, 0x07060302u);       // [lo[31:16], hi[31:16]]
}
#endif

__global__ __launch_bounds__(THREADS, 4)
void setconv_kernel(const float* __restrict__ x,       // [2][4096][2]
                    const float* __restrict__ z,       // [2][4096][64]
                    const float* __restrict__ x_grid,  // [2][16384][2]
                    const float* __restrict__ z_grid,  // [2][16384][64]
                    const float* __restrict__ lsp,     // [2]
                    float* __restrict__ out)           // [2][16384][64], memset to 0
{
    __shared__ __align__(16) unsigned char lds[2 * BUF_B];

    const int tid  = threadIdx.x;
    const int wave = tid >> 6;
    const int lane = tid & 63;
    const int quad = lane >> 4;
    const int l16  = lane & 15;

    const int mb    = blockIdx.y;
    const int gbase = blockIdx.x * BG;
    const int nbase = blockIdx.z * NCHUNK;

    const float LOG2E = 1.44269504088896340736f;
    const float inv0 = 1.0f / (1e-5f + log1pf(__expf(lsp[0])));
    const float inv1 = 1.0f / (1e-5f + log1pf(__expf(lsp[1])));
    const f32x2 inv02 = (f32x2){inv0, inv0};
    const f32x2 inv12 = (f32x2){inv1, inv1};
    const f32x2 nh2   = (f32x2){-0.5f * LOG2E, -0.5f * LOG2E};

    // 2 row-groups per wave: rows wave*32 + g*16 + l16 (splat to f32x2 for pk math).
    f32x2 qx2[2], qy2[2], hq2[2];
#pragma unroll
    for (int g = 0; g < 2; g++) {
        const int grow = gbase + wave * 32 + g * 16 + l16;
        const float2 qraw = *(const float2*)&x_grid[(size_t)(mb * G_TOT + grow) * 2];
        const float qx = qraw.x * inv0, qy = qraw.y * inv1;
        const float qxL = LOG2E * qx, qyL = LOG2E * qy;
        const float hq  = -0.5f * LOG2E * (qx * qx + qy * qy);
        qx2[g] = (f32x2){qxL, qxL};
        qy2[g] = (f32x2){qyL, qyL};
        hq2[g] = (f32x2){hq, hq};
    }

    // z staging: sdzg = dz-group of 4 (consecutive lanes -> consecutive dz ->
    // 256B-coalesced float4 global loads), snq = n-quad (n = snq*4 + j).
    const int sdzg = tid & 15;
    const int snq  = tid >> 4;     // 0..15
    const float* zb = z + (size_t)mb * N_TOT * DZ + sdzg * 4;
    // Write offsets: row d = sdzg*4+i, logical block = snq>>1, sub = (snq&1)*8,
    // phys = (snq>>1) ^ ((2*(sdzg&3) + (i>>1)) & 7) ^ (sdzg>>2).
    unsigned wr_off[4];
#pragma unroll
    for (int i = 0; i < 4; i++) {
        const unsigned swz  = ((2u * (sdzg & 3) + (i >> 1)) & 7u) ^ (unsigned)(sdzg >> 2);
        const unsigned phys = ((unsigned)(snq >> 1)) ^ swz;
        wr_off[i] = (unsigned)(sdzg * 4 + i) * ZROW_B + phys * 16 + (unsigned)(snq & 1) * 8;
    }

    // B-frag read bases: row r = nt*16 + l16 -> swz = ((l16>>1)&7) ^ nt;
    // block = quad ^ (kc<<2). addr = l16*128 + nt*2048 + ((quad^(kc<<2)^swz^nt)*16).
    const unsigned swz_l = (unsigned)((l16 >> 1) & 7);
    const unsigned rbA   = (unsigned)l16 * ZROW_B + ((unsigned)quad ^ swz_l) * 16;  // kc=0, nt=0
    const unsigned rbB   = rbA ^ (4u * 16u);                                        // kc=1, nt=0

    f32x4 acc[2][4];
#pragma unroll
    for (int g = 0; g < 2; g++)
#pragma unroll
        for (int i = 0; i < 4; i++) acc[g][i] = (f32x4){0.f, 0.f, 0.f, 0.f};

    // k-coordinate loads: quad-uniform addresses -> L1 broadcast. PREFETCHED one
    // iteration ahead into registers so consumption never drains the z-prefetch.
    const float* xk = x + (size_t)mb * N_TOT * 2;
    auto loadk = [&](int n0, float4* kf) {
#pragma unroll
        for (int kc = 0; kc < 2; kc++)
#pragma unroll
            for (int j = 0; j < 4; j++)   // float4 = coords of n-pair (2j, 2j+1)
                kf[kc * 4 + j] =
                    *(const float4*)(xk + (size_t)(n0 + kc * 32 + quad * 8 + j * 2) * 2);
    };
    auto loadz = [&](int n0, float4* zf) {
        const float* zp = zb + (size_t)(n0 + snq * 4) * DZ;
#pragma unroll
        for (int j = 0; j < 4; j++) zf[j] = *(const float4*)(zp + j * DZ);
    };
    auto stagez = [&](unsigned dst, const float4* zf) {
#pragma unroll
        for (int i = 0; i < 4; i++) {
            uint2 w;
            w.x = pack_bf16_pair(zf[0][i], zf[1][i]);
            w.y = pack_bf16_pair(zf[2][i], zf[3][i]);
            *(uint2*)(lds + dst + wr_off[i]) = w;
        }
    };

    // ---- prologue: fetch + stage tile 0; prefetch k for tile 0 ----
    float4 kf[8], zf[4];
    loadk(nbase, kf);
    loadz(nbase, zf);
    stagez(0u, zf);
    __syncthreads();

    for (int t = 0; t < ITERS; t++) {
        const unsigned bo = (unsigned)((t & 1) ? BUF_B : 0);
        const unsigned bn = bo ^ (unsigned)BUF_B;

        // ---- issue next tile's global loads (z first, then k; both land during
        //      this iteration's compute -> consumed next iter with vmcnt(N>0)) ----
        float4 kfn[8], zfn[4];
        if (t + 1 < ITERS) {
            const int nb1 = nbase + (t + 1) * BN;
            loadz(nb1, zfn);
            loadk(nb1, kfn);
        }

        // ---- compute tile t (kf loaded LAST iteration -> no z-prefetch drain) ----
#pragma unroll
        for (int kc = 0; kc < 2; kc++) {
            // B-frags once per kc, reused by both row-groups.
            short8 bf[4];
            const unsigned rb = bo + ((kc == 0) ? rbA : rbB);
#pragma unroll
            for (int nt = 0; nt < 4; nt++)
                bf[nt] = *(const short8*)(lds + (rb ^ (unsigned)(nt * 16)) + nt * (16 * ZROW_B));

            // k-prep in registers (packed): u=kx/ls0, v=ky/ls1, hb=-0.5L(u^2+v^2).
            f32x2 u2[4], v2[4], hb2[4];
#pragma unroll
            for (int j = 0; j < 4; j++) {
                const float4 f = kf[kc * 4 + j];   // (kx0,ky0,kx1,ky1)
                u2[j] = (f32x2){f.x, f.z} * inv02;
                v2[j] = (f32x2){f.y, f.w} * inv12;
                f32x2 tt = u2[j] * u2[j];
                tt = __builtin_elementwise_fma(v2[j], v2[j], tt);
                hb2[j] = tt * nh2;
            }

            // Scores (v_pk_fma_f32) -> exp2 -> bf16 A-frags -> 8 MFMA.
#pragma unroll
            for (int g = 0; g < 2; g++) {
                unsigned aw[4];
#pragma unroll
                for (int j = 0; j < 4; j++) {
                    f32x2 s = hq2[g] + hb2[j];
                    s = __builtin_elementwise_fma(qy2[g], v2[j], s);
                    s = __builtin_elementwise_fma(qx2[g], u2[j], s);
                    aw[j] = pack_bf16_pair(__builtin_amdgcn_exp2f(s.x),
                                           __builtin_amdgcn_exp2f(s.y));
                }
                const int4v  av = {(int)aw[0], (int)aw[1], (int)aw[2], (int)aw[3]};
                const short8 af = __builtin_bit_cast(short8, av);
#pragma unroll
                for (int nt = 0; nt < 4; nt++)
                    acc[g][nt] = __builtin_amdgcn_mfma_f32_16x16x32_bf16(af, bf[nt], acc[g][nt], 0, 0, 0);
            }
        }

        // ---- stage next tile into buffer bn; single barrier per iteration ----
        if (t + 1 < ITERS) {
            stagez(bn, zfn);
            __syncthreads();
#pragma unroll
            for (int h = 0; h < 8; h++) kf[h] = kfn[h];
        }
    }

    // ---- epilogue: C/D layout col = lane&15 (dz), row = quad*4 + reg (g-row) ----
    // out was memset to 0; 4 n-splits combine via atomics. Split 0 folds z_grid in.
    const bool add_zg = (blockIdx.z == 0);
#pragma unroll
    for (int g = 0; g < 2; g++) {
        const int gout = gbase + wave * 32 + g * 16 + quad * 4;
#pragma unroll
        for (int nt = 0; nt < 4; nt++) {
#pragma unroll
            for (int r = 0; r < 4; r++) {
                const size_t idx = (size_t)(mb * G_TOT + gout + r) * DZ + nt * 16 + l16;
                const float v = add_zg ? (acc[g][nt][r] + z_grid[idx]) : acc[g][nt][r];
                atomicAdd(&out[idx], v);
            }
        }
    }
}

extern "C" void kernel_launch(void* const* d_in, const int* in_sizes, int n_in,
                              void* d_out, int out_size, void* d_ws, size_t ws_size,
                              hipStream_t stream) {
    const float* x   = (const float*)d_in[0];
    const float* z   = (const float*)d_in[1];
    const float* xg  = (const float*)d_in[2];
    const float* zgr = (const float*)d_in[3];
    const float* lsp = (const float*)d_in[4];
    float* out = (float*)d_out;

    // out = 0 (write-only memset node; z_grid folded in by split 0's atomics)
    hipMemsetAsync(out, 0, sizeof(float) * (size_t)M_TOT * G_TOT * DZ, stream);

    dim3 grid(G_TOT / BG, M_TOT, NSPLIT);
    setconv_kernel<<<grid, THREADS, 0, stream>>>(x, z, xg, zgr, lsp, out);
}